// Round 15
// baseline (52.576 us; speedup 1.0000x reference)
//
#include <hip/hip_runtime.h>
#include <hip/hip_bf16.h>
#include <cstdint>
#include <cstddef>

typedef __attribute__((ext_vector_type(8))) short bf16x8;
typedef __attribute__((ext_vector_type(4))) float f32x4;

__device__ __forceinline__ unsigned short f2bf(float f) {
  union { float f; unsigned u; } v; v.f = f;
  unsigned r = v.u + 0x7FFFu + ((v.u >> 16) & 1u);
  return (unsigned short)(r >> 16);
}

__device__ __forceinline__ float bf2f(unsigned short h) {
  union { float f; unsigned u; } c; c.u = ((unsigned)h) << 16;
  return c.f;
}

__device__ __forceinline__ void gload_lds16(const void* g, void* l) {
  __builtin_amdgcn_global_load_lds(
      (const __attribute__((address_space(1))) unsigned int*)g,
      (__attribute__((address_space(3))) unsigned int*)l, 16, 0, 0);
}

// ---------------------------------------------------------------------------
// K01: 256 blocks x 1024 thr. W-tile loads hoisted to regs; x-phase norms/
// converts 32 rows; per-block s-partial written with PLAIN STORES to
// sp[b][1024] (NO atomics -- R14 diagnosis: 262K device-scope RMWs into one
// 4KB buffer serialize at the coherence point). No memset needed anywhere.
// ---------------------------------------------------------------------------
__global__ __launch_bounds__(1024) void k01_prep(const float* __restrict__ W,
                                                 unsigned short* __restrict__ Wt,
                                                 const float* __restrict__ x,
                                                 unsigned short* __restrict__ xbf,
                                                 float* __restrict__ rnorm,
                                                 float* __restrict__ sp) {
  __shared__ __align__(16) char sm[82176];
  int tid = threadIdx.x;
  int b = blockIdx.x;
  int lane = tid & 63;
  int wid = tid >> 6;  // 0..15

  int k0 = (b & 15) * 64;
  int c0 = (b >> 4) * 64;
  int tx = tid & 63;
  int ty = tid >> 6;
  float wreg[4];
#pragma unroll
  for (int i = 0; i < 4; ++i) {
    int c = c0 + tx;
    wreg[i] = (c < 1000) ? W[(size_t)(k0 + i * 16 + ty) * 1000 + c] : 0.f;
  }

  {
    float (*sblk)[1024] = (float(*)[1024])sm;
    int row0 = b * 32 + wid * 2;
    const float4* xr0 = (const float4*)(x + (size_t)row0 * 1024);
    const float4* xr1 = (const float4*)(x + (size_t)(row0 + 1) * 1024);
    float4 v[2][4];
#pragma unroll
    for (int j = 0; j < 4; ++j) v[0][j] = xr0[lane + j * 64];
#pragma unroll
    for (int j = 0; j < 4; ++j) v[1][j] = xr1[lane + j * 64];
    float ss0 = 0.f, ss1 = 0.f;
#pragma unroll
    for (int j = 0; j < 4; ++j) {
      ss0 += v[0][j].x * v[0][j].x + v[0][j].y * v[0][j].y +
             v[0][j].z * v[0][j].z + v[0][j].w * v[0][j].w;
      ss1 += v[1][j].x * v[1][j].x + v[1][j].y * v[1][j].y +
             v[1][j].z * v[1][j].z + v[1][j].w * v[1][j].w;
    }
#pragma unroll
    for (int m = 1; m < 64; m <<= 1) {
      ss0 += __shfl_xor(ss0, m);
      ss1 += __shfl_xor(ss1, m);
    }
    float rn0 = 1.f / fmaxf(sqrtf(ss0), 1e-8f);
    float rn1 = 1.f / fmaxf(sqrtf(ss1), 1e-8f);
    if (lane == 0) {
      rnorm[row0] = rn0;
      rnorm[row0 + 1] = rn1;
    }
    float4 sacc[4];
#pragma unroll
    for (int j = 0; j < 4; ++j) {
      ushort4 h0, h1;
      h0.x = f2bf(v[0][j].x); h0.y = f2bf(v[0][j].y);
      h0.z = f2bf(v[0][j].z); h0.w = f2bf(v[0][j].w);
      h1.x = f2bf(v[1][j].x); h1.y = f2bf(v[1][j].y);
      h1.z = f2bf(v[1][j].z); h1.w = f2bf(v[1][j].w);
      ((ushort4*)(xbf + (size_t)row0 * 1024))[lane + j * 64] = h0;
      ((ushort4*)(xbf + (size_t)(row0 + 1) * 1024))[lane + j * 64] = h1;
      sacc[j].x = v[0][j].x * rn0 + v[1][j].x * rn1;
      sacc[j].y = v[0][j].y * rn0 + v[1][j].y * rn1;
      sacc[j].z = v[0][j].z * rn0 + v[1][j].z * rn1;
      sacc[j].w = v[0][j].w * rn0 + v[1][j].w * rn1;
    }
#pragma unroll
    for (int j = 0; j < 4; ++j) ((float4*)sblk[wid])[j * 64 + lane] = sacc[j];
    __syncthreads();
    float acc = 0.f;
#pragma unroll
    for (int w = 0; w < 16; ++w) acc += sblk[w][tid];
    sp[(size_t)b * 1024 + tid] = acc;  // plain store, no RMW
  }

  {
    float (*tile)[65] = (float(*)[65])(sm + 65536);
#pragma unroll
    for (int i = 0; i < 4; ++i) tile[i * 16 + ty][tx] = wreg[i];
    __syncthreads();
#pragma unroll
    for (int i = 0; i < 4; ++i) {
      int ct = i * 16 + ty;
      Wt[(size_t)(c0 + ct) * 1024 + (k0 + tx)] = f2bf(tile[tx][ct]);
    }
  }
}

// ---------------------------------------------------------------------------
// K2: reduce sp[256][1024] -> s[1024]. 16 blocks x 256 thr; block j owns
// d in [j*64, j*64+64); thread group g (of 4) sums 64 b's; LDS combine.
// ---------------------------------------------------------------------------
__global__ __launch_bounds__(256) void k2_sred(const float* __restrict__ sp,
                                               float* __restrict__ s) {
  __shared__ float red[4][64];
  int t = threadIdx.x;
  int dd = t & 63;
  int g = t >> 6;
  int d = blockIdx.x * 64 + dd;
  float acc = 0.f;
#pragma unroll 8
  for (int b = g * 64; b < g * 64 + 64; ++b) acc += sp[(size_t)b * 1024 + d];
  red[g][dd] = acc;
  __syncthreads();
  if (g == 0) s[d] = red[0][dd] + red[1][dd] + red[2][dd] + red[3][dd];
}

// ---------------------------------------------------------------------------
// K3: m97-replica GEMM + softmax partials. 128x128 tile, 256 thr (4 waves,
// wave = 64x64), BK=64, DOUBLE-buffered 64KB LDS -> 2 blocks/CU (cross-block
// overlap absorbs the vmcnt(0) barrier drain -- the mechanism every 1-blk/CU
// schedule variant lacked). XOR-swizzle via inverse-swizzled global source;
// XCD-aligned cb=b>>6, rb=b&63 (row-panel's 8 cls-blocks on one XCD).
// ---------------------------------------------------------------------------
__global__ __launch_bounds__(256) void k3_gemm(const unsigned short* __restrict__ xbf,
                                               const unsigned short* __restrict__ wt,
                                               const float* __restrict__ bias,
                                               float* __restrict__ pm,
                                               float* __restrict__ pz,
                                               float* __restrict__ ps) {
  __shared__ __align__(16) char lds[65536];  // 2 x (A 16KB + B 16KB)

  int tid = threadIdx.x;
  int lane = tid & 63;
  int wid = tid >> 6;  // 0..3
  int wc = wid & 1;    // cls half
  int wr = wid >> 1;   // row half
  int cb = blockIdx.x >> 6;  // 0..7
  int rb = blockIdx.x & 63;  // 0..63 -> XCD = rb % 8
  int C0 = cb * 128;
  int R0 = rb * 128;

  float bv[4][4];
#pragma unroll
  for (int mf = 0; mf < 4; ++mf)
#pragma unroll
    for (int q = 0; q < 4; ++q) {
      int cls_g = C0 + wc * 64 + mf * 16 + (lane >> 4) * 4 + q;
      bv[mf][q] = (cls_g < 1000) ? bias[cls_g] : -1e30f;
    }
  f32x4 acc[4][4];
#pragma unroll
  for (int mf = 0; mf < 4; ++mf)
#pragma unroll
    for (int nf = 0; nf < 4; ++nf)
#pragma unroll
      for (int q = 0; q < 4; ++q) acc[mf][nf][q] = bv[mf][q];

  const char* gA = (const char*)(wt + (size_t)C0 * 1024);
  const char* gB = (const char*)(xbf + (size_t)R0 * 1024);
  int grow = (tid >> 3) & 7;                 // row&7 within any 32-row group
  int gswz = ((tid & 7) ^ grow) << 4;        // inverse-swizzled k-byte

  // stage tile kt into buf bb: A 4 rounds + B 4 rounds; dest linear.
  auto stage = [&](int kt, int bb) {
    char* lA = lds + bb * 32768;
    char* lB = lA + 16384;
#pragma unroll
    for (int i = 0; i < 4; ++i) {
      size_t row = i * 32 + (tid >> 3);
      gload_lds16(gA + row * 2048 + kt * 128 + gswz, lA + i * 4096 + tid * 16);
    }
#pragma unroll
    for (int i = 0; i < 4; ++i) {
      size_t row = i * 32 + (tid >> 3);
      gload_lds16(gB + row * 2048 + kt * 128 + gswz, lB + i * 4096 + tid * 16);
    }
  };

  int rsw = (lane & 7) << 4;
  int kcol = (lane >> 4) * 16;

  stage(0, 0);
  __syncthreads();
  int cur = 0;
  for (int t = 0; t < 16; ++t) {
    if (t < 15) stage(t + 1, cur ^ 1);
    const char* A = lds + cur * 32768;
    const char* B = A + 16384;
    bf16x8 a[4][2], bb[4][2];
#pragma unroll
    for (int mf = 0; mf < 4; ++mf)
#pragma unroll
      for (int ks = 0; ks < 2; ++ks)
        a[mf][ks] = *(const bf16x8*)(A + (wc * 64 + mf * 16 + (lane & 15)) * 128 +
                                     ((ks * 64 + kcol) ^ rsw));
#pragma unroll
    for (int nf = 0; nf < 4; ++nf)
#pragma unroll
      for (int ks = 0; ks < 2; ++ks)
        bb[nf][ks] = *(const bf16x8*)(B + (wr * 64 + nf * 16 + (lane & 15)) * 128 +
                                      ((ks * 64 + kcol) ^ rsw));
    __builtin_amdgcn_s_setprio(1);
#pragma unroll
    for (int ks = 0; ks < 2; ++ks)
#pragma unroll
      for (int mf = 0; mf < 4; ++mf)
#pragma unroll
        for (int nf = 0; nf < 4; ++nf)
          acc[mf][nf] = __builtin_amdgcn_mfma_f32_16x16x32_bf16(a[mf][ks], bb[nf][ks],
                                                                acc[mf][nf], 0, 0, 0);
    __builtin_amdgcn_s_setprio(0);
    __syncthreads();
    cur ^= 1;
  }

  // epilogue: per-row stats over wave's 64 cls; merge the two wc halves.
  float* mm = (float*)lds;
  float* zz = mm + 256;
  float* sv = zz + 256;
#pragma unroll
  for (int nf = 0; nf < 4; ++nf) {
    float m1 = -1e30f;
#pragma unroll
    for (int mf = 0; mf < 4; ++mf)
#pragma unroll
      for (int q = 0; q < 4; ++q) m1 = fmaxf(m1, acc[mf][nf][q]);
    m1 = fmaxf(m1, __shfl_xor(m1, 16));
    m1 = fmaxf(m1, __shfl_xor(m1, 32));
    float z1 = 0.f, s1 = 0.f;
#pragma unroll
    for (int mf = 0; mf < 4; ++mf)
#pragma unroll
      for (int q = 0; q < 4; ++q) {
        float tt = acc[mf][nf][q] - m1;
        float e = expf(tt);
        z1 += e;
        s1 += e * tt;
      }
    z1 += __shfl_xor(z1, 16); z1 += __shfl_xor(z1, 32);
    s1 += __shfl_xor(s1, 16); s1 += __shfl_xor(s1, 32);
    if (lane < 16) {
      int r = wr * 64 + nf * 16 + lane;
      mm[wc * 128 + r] = m1;
      zz[wc * 128 + r] = z1;
      sv[wc * 128 + r] = s1;
    }
  }
  __syncthreads();
  if (tid < 128) {
    float m0 = mm[tid], mA = mm[128 + tid];
    float z0 = zz[tid], zA = zz[128 + tid];
    float s0 = sv[tid], sA = sv[128 + tid];
    float M = fmaxf(m0, mA);
    float e0 = expf(m0 - M), e1 = expf(mA - M);
    float Z = z0 * e0 + zA * e1;
    float S = e0 * (s0 + (m0 - M) * z0) + e1 * (sA + (mA - M) * zA);
    size_t o = (size_t)cb * 8192 + R0 + tid;
    pm[o] = M;
    pz[o] = Z;
    ps[o] = S;
  }
}

// ---------------------------------------------------------------------------
// K4: parallel merge (R12-proven): 2048 blocks x 256 thr, one wave per row.
// ---------------------------------------------------------------------------
__global__ __launch_bounds__(256) void k4_final(const unsigned short* __restrict__ xbf,
                                                const float* __restrict__ s,
                                                const float* __restrict__ rnorm,
                                                const float* __restrict__ pm,
                                                const float* __restrict__ pz,
                                                const float* __restrict__ ps,
                                                float* __restrict__ out) {
  int tid = threadIdx.x;
  int wid = tid >> 6, lane = tid & 63;
  int row = blockIdx.x * 4 + wid;
  const bf16x8* xr = (const bf16x8*)(xbf + (size_t)row * 1024);
  const float4* s4 = (const float4*)s;
  float dot = 0.f;
#pragma unroll
  for (int j = 0; j < 2; ++j) {
    bf16x8 v = xr[lane + j * 64];
    float4 sa = s4[(lane + j * 64) * 2];
    float4 sb = s4[(lane + j * 64) * 2 + 1];
    dot += bf2f((unsigned short)v[0]) * sa.x + bf2f((unsigned short)v[1]) * sa.y +
           bf2f((unsigned short)v[2]) * sa.z + bf2f((unsigned short)v[3]) * sa.w +
           bf2f((unsigned short)v[4]) * sb.x + bf2f((unsigned short)v[5]) * sb.y +
           bf2f((unsigned short)v[6]) * sb.z + bf2f((unsigned short)v[7]) * sb.w;
  }
#pragma unroll
  for (int m = 1; m < 64; m <<= 1) dot += __shfl_xor(dot, m);
  if (lane == 0) {
    float mv[8], zv[8], svv[8];
    float M = -1e30f;
#pragma unroll
    for (int c = 0; c < 8; ++c) {
      mv[c] = pm[(size_t)c * 8192 + row];
      zv[c] = pz[(size_t)c * 8192 + row];
      svv[c] = ps[(size_t)c * 8192 + row];
      M = fmaxf(M, mv[c]);
    }
    float Z = 0.f, S = 0.f;
#pragma unroll
    for (int c = 0; c < 8; ++c) {
      float e = expf(mv[c] - M);
      Z += zv[c] * e;
      S += e * (svv[c] + (mv[c] - M) * zv[c]);
    }
    float loss = S / Z - logf(Z);
    out[row] = loss * dot * rnorm[row] * (1.f / 8192.f);
  }
}

// ---------------------------------------------------------------------------
extern "C" void kernel_launch(void* const* d_in, const int* in_sizes, int n_in,
                              void* d_out, int out_size, void* d_ws, size_t ws_size,
                              hipStream_t stream) {
  (void)in_sizes; (void)n_in; (void)out_size; (void)ws_size;
  const float* x = (const float*)d_in[0];
  const float* W = (const float*)d_in[1];
  const float* b = (const float*)d_in[2];
  float* out = (float*)d_out;
  char* ws = (char*)d_ws;

  unsigned short* Wt = (unsigned short*)(ws + 0);           // 2 MiB
  unsigned short* xbf = (unsigned short*)(ws + 2097152);    // 16 MiB
  float* rnorm = (float*)(ws + 18874368);                   // 32 KiB
  float* s = (float*)(ws + 18907136);                       // 4 KiB
  // sp (1 MiB) aliases the pm/pz/ps region: sp dead after k2, pm born in k3.
  float* sp = (float*)(ws + 18915328);
  float* pm = (float*)(ws + 18915328);                      // 256 KiB
  float* pz = (float*)(ws + 18915328 + 262144);
  float* ps = (float*)(ws + 18915328 + 524288);

  // no memset needed: no atomics, no counters; every buffer fully written
  // before it is read, every replay.
  k01_prep<<<256, 1024, 0, stream>>>(W, Wt, x, xbf, rnorm, sp);
  k2_sred<<<16, 256, 0, stream>>>(sp, s);
  k3_gemm<<<512, 256, 0, stream>>>(xbf, Wt, b, pm, pz, ps);
  k4_final<<<2048, 256, 0, stream>>>(xbf, s, rnorm, pm, pz, ps, out);
}